// Round 1
// baseline (1402.980 us; speedup 1.0000x reference)
//
#include <hip/hip_runtime.h>
#include <stdint.h>

#define NN 100000
#define EE 1600000
#define DD 256

// ---------------------------------------------------------------------------
// Mask dtype probe: masks are jnp.bool_. Harness may push them as 1-byte bool,
// int32 (0/1) or f32 (0/1.0f). Read first 64 words: if any word is not in
// {0, 1, 0x3F800000} the data must be byte-packed. (P[false-negative] ~ 8^-64.)
// For 4-byte modes, "word != 0" decodes both int32 1 and f32 1.0f.
// ---------------------------------------------------------------------------
__global__ void probe_mask_k(const unsigned int* __restrict__ m, int* __restrict__ flag) {
    unsigned int v = m[threadIdx.x];
    int bad = (v > 1u && v != 0x3F800000u) ? 1 : 0;
    unsigned long long b = __ballot(bad);
    if (threadIdx.x == 0) *flag = (b != 0ull) ? 1 : 0;
}

__device__ __forceinline__ void apply_mask4(float4& v, const void* __restrict__ mask,
                                            size_t idx, int byteMode) {
    float m0, m1, m2, m3;
    if (byteMode) {
        uchar4 u = *(const uchar4*)((const unsigned char*)mask + idx);
        m0 = u.x ? 2.0f : 0.0f; m1 = u.y ? 2.0f : 0.0f;
        m2 = u.z ? 2.0f : 0.0f; m3 = u.w ? 2.0f : 0.0f;
    } else {
        uint4 u = *(const uint4*)((const unsigned int*)mask + idx);
        m0 = u.x ? 2.0f : 0.0f; m1 = u.y ? 2.0f : 0.0f;
        m2 = u.z ? 2.0f : 0.0f; m3 = u.w ? 2.0f : 0.0f;
    }
    v.x *= m0; v.y *= m1; v.z *= m2; v.w *= m3;
}

// ---------------------------------------------------------------------------
// GCN-norm + CSR build
// ---------------------------------------------------------------------------
__global__ void init_deg_k(int* __restrict__ cnt) {
    int i = blockIdx.x * 256 + threadIdx.x;
    if (i < NN) cnt[i] = 1;                       // self-loop
}

__global__ void count_deg_k(const int* __restrict__ dst, int* __restrict__ cnt) {
    int e = blockIdx.x * 256 + threadIdx.x;
    if (e < EE) atomicAdd(&cnt[dst[e]], 1);
}

__global__ void dinv_k(const int* __restrict__ cnt, float* __restrict__ dinv) {
    int i = blockIdx.x * 256 + threadIdx.x;
    if (i < NN) dinv[i] = rsqrtf((float)cnt[i]);
}

// single-block grid-serial exclusive scan of cnt[N] -> offs[N+1]
__global__ __launch_bounds__(1024) void scan_k(const int* __restrict__ cnt,
                                               int* __restrict__ offs) {
    __shared__ int buf[1024];
    __shared__ int carry_s;
    if (threadIdx.x == 0) carry_s = 0;
    __syncthreads();
    for (int base = 0; base < NN; base += 1024) {
        int i = base + threadIdx.x;
        int v = (i < NN) ? cnt[i] : 0;
        buf[threadIdx.x] = v;
        __syncthreads();
        for (int off = 1; off < 1024; off <<= 1) {
            int t = (threadIdx.x >= off) ? buf[threadIdx.x - off] : 0;
            __syncthreads();
            buf[threadIdx.x] += t;
            __syncthreads();
        }
        int c = carry_s;
        if (i < NN) offs[i + 1] = c + buf[threadIdx.x];
        __syncthreads();
        if (threadIdx.x == 0) carry_s = c + buf[1023];
        __syncthreads();
    }
    if (threadIdx.x == 0) offs[0] = 0;
}

__global__ void copy_cursor_k(const int* __restrict__ offs, int* __restrict__ cur) {
    int i = blockIdx.x * 256 + threadIdx.x;
    if (i < NN) cur[i] = offs[i];
}

__global__ void fill_csr_k(const int* __restrict__ src, const int* __restrict__ dst,
                           const float* __restrict__ dinv, int* __restrict__ cur,
                           int* __restrict__ cs, float* __restrict__ cw) {
    int e = blockIdx.x * 256 + threadIdx.x;
    if (e >= EE) return;
    int s = src[e], d = dst[e];
    int pos = atomicAdd(&cur[d], 1);
    cs[pos] = s;
    cw[pos] = dinv[s] * dinv[d];
}

__global__ void fill_self_k(const float* __restrict__ dinv, int* __restrict__ cur,
                            int* __restrict__ cs, float* __restrict__ cw) {
    int i = blockIdx.x * 256 + threadIdx.x;
    if (i >= NN) return;
    int pos = atomicAdd(&cur[i], 1);
    cs[pos] = i;
    float di = dinv[i];
    cw[pos] = di * di;
}

// ---------------------------------------------------------------------------
// fp32 GEMM: out[M,256] = A[M,256] @ W[256,256]  (+ fused epilogue)
// BM=64, BN=256 (full), BK=32, 256 threads, 8x8 per thread.
// EPI: 0 = raw store, 1 = bias + relu + dropout(mask)
// ---------------------------------------------------------------------------
template <int EPI>
__global__ __launch_bounds__(256) void gemm64_k(
    const float* __restrict__ A, const float* __restrict__ W,
    const float* __restrict__ bias, const void* __restrict__ mask,
    const int* __restrict__ flagp, float* __restrict__ out) {
    const int BM = 64, BK = 32;
    __shared__ float As[BK][BM];     // A transposed: As[k][m]
    __shared__ float Bs[BK][DD];

    int tid = threadIdx.x;
    int m0 = blockIdx.x * BM;
    int ty = tid >> 5;   // 0..7  (row group of 8)
    int tx = tid & 31;   // 0..31 (col group of 8)

    float acc[8][8] = {};

    for (int k0 = 0; k0 < DD; k0 += BK) {
        // A tile: 64x32 floats = 512 float4, 2 per thread
        #pragma unroll
        for (int i = 0; i < 2; i++) {
            int f = tid + i * 256;
            int row = f >> 3;
            int c4  = f & 7;
            int gr = m0 + row;
            float4 v = {0.f, 0.f, 0.f, 0.f};
            if (gr < NN) v = *(const float4*)(A + (size_t)gr * DD + k0 + c4 * 4);
            As[c4 * 4 + 0][row] = v.x;
            As[c4 * 4 + 1][row] = v.y;
            As[c4 * 4 + 2][row] = v.z;
            As[c4 * 4 + 3][row] = v.w;
        }
        // B tile: 32x256 floats = 2048 float4, 8 per thread
        #pragma unroll
        for (int i = 0; i < 8; i++) {
            int f = tid + i * 256;
            int row = f >> 6;
            int c4  = f & 63;
            *(float4*)(&Bs[row][c4 * 4]) =
                *(const float4*)(W + (size_t)(k0 + row) * DD + c4 * 4);
        }
        __syncthreads();

        #pragma unroll
        for (int kk = 0; kk < BK; kk++) {
            float a[8], b[8];
            *(float4*)(a)     = *(const float4*)(&As[kk][ty * 8]);
            *(float4*)(a + 4) = *(const float4*)(&As[kk][ty * 8 + 4]);
            *(float4*)(b)     = *(const float4*)(&Bs[kk][tx * 8]);
            *(float4*)(b + 4) = *(const float4*)(&Bs[kk][tx * 8 + 4]);
            #pragma unroll
            for (int r = 0; r < 8; r++)
                #pragma unroll
                for (int c = 0; c < 8; c++)
                    acc[r][c] = fmaf(a[r], b[c], acc[r][c]);
        }
        __syncthreads();
    }

    int bm = (EPI == 1) ? *flagp : 0;
    #pragma unroll
    for (int r = 0; r < 8; r++) {
        int gr = m0 + ty * 8 + r;
        if (gr < NN) {
            #pragma unroll
            for (int c = 0; c < 8; c += 4) {
                int gc = tx * 8 + c;
                float4 v = {acc[r][c], acc[r][c + 1], acc[r][c + 2], acc[r][c + 3]};
                if (EPI == 1) {
                    float4 b = *(const float4*)(bias + gc);
                    v.x = fmaxf(v.x + b.x, 0.f);
                    v.y = fmaxf(v.y + b.y, 0.f);
                    v.z = fmaxf(v.z + b.z, 0.f);
                    v.w = fmaxf(v.w + b.w, 0.f);
                    apply_mask4(v, mask, (size_t)gr * DD + gc, bm);
                }
                *(float4*)(out + (size_t)gr * DD + gc) = v;
            }
        }
    }
}

// ---------------------------------------------------------------------------
// CSR pull aggregation: out[n,:] = sum_e w[e] * t[src[e],:]  (+ epilogue)
// One wave per node; lane owns 4 columns (float4).
// EPI: 1 = +bias, relu, dropout(mask)  2 = +bias, * z  3 = +bias only
// ---------------------------------------------------------------------------
template <int EPI>
__global__ __launch_bounds__(256) void agg_k(
    const float* __restrict__ t, const int* __restrict__ offs,
    const int* __restrict__ cs, const float* __restrict__ cw,
    const float* __restrict__ bias, const void* __restrict__ mask,
    const int* __restrict__ flagp, const float* __restrict__ z,
    float* __restrict__ out) {
    int node = blockIdx.x * 4 + (threadIdx.x >> 6);
    if (node >= NN) return;
    int lane = threadIdx.x & 63;
    int beg = offs[node], end = offs[node + 1];

    float4 acc = {0.f, 0.f, 0.f, 0.f};
    for (int base = beg; base < end; base += 64) {
        int nume = min(64, end - base);
        int sl = 0; float wl = 0.f;
        if (lane < nume) { sl = cs[base + lane]; wl = cw[base + lane]; }
        for (int j = 0; j < nume; j++) {
            int s   = __shfl(sl, j);
            float w = __shfl(wl, j);
            float4 v = *(const float4*)(t + (size_t)s * DD + lane * 4);
            acc.x = fmaf(w, v.x, acc.x);
            acc.y = fmaf(w, v.y, acc.y);
            acc.z = fmaf(w, v.z, acc.z);
            acc.w = fmaf(w, v.w, acc.w);
        }
    }

    int col = lane * 4;
    float4 b = *(const float4*)(bias + col);
    acc.x += b.x; acc.y += b.y; acc.z += b.z; acc.w += b.w;

    size_t idx = (size_t)node * DD + col;
    if (EPI == 1) {
        acc.x = fmaxf(acc.x, 0.f); acc.y = fmaxf(acc.y, 0.f);
        acc.z = fmaxf(acc.z, 0.f); acc.w = fmaxf(acc.w, 0.f);
        apply_mask4(acc, mask, idx, *flagp);
    } else if (EPI == 2) {
        float4 zz = *(const float4*)(z + idx);
        acc.x *= zz.x; acc.y *= zz.y; acc.z *= zz.z; acc.w *= zz.w;
    }
    *(float4*)(out + idx) = acc;
}

__global__ void mulz_k(const float* __restrict__ z, const float* __restrict__ h,
                       float* __restrict__ out) {
    int i = blockIdx.x * 256 + threadIdx.x;
    if (i < NN * DD / 4) {
        float4 a = ((const float4*)z)[i];
        float4 b = ((const float4*)h)[i];
        float4 r = {a.x * b.x, a.y * b.y, a.z * b.z, a.w * b.w};
        ((float4*)out)[i] = r;
    }
}

// ---------------------------------------------------------------------------
extern "C" void kernel_launch(void* const* d_in, const int* in_sizes, int n_in,
                              void* d_out, int out_size, void* d_ws, size_t ws_size,
                              hipStream_t stream) {
    const float* z     = (const float*)d_in[0];
    const float* omega = (const float*)d_in[1];
    const int*   eidx  = (const int*)d_in[2];
    const float* W_lin = (const float*)d_in[3];
    const float* b_lin = (const float*)d_in[4];
    const float* W_g1  = (const float*)d_in[5];
    const float* b_g1  = (const float*)d_in[6];
    const float* W_g2  = (const float*)d_in[7];
    const float* b_g2  = (const float*)d_in[8];
    const void*  mask1 = d_in[9];
    const void*  mask2 = d_in[10];

    const int* e_src = eidx;
    const int* e_dst = eidx + EE;

    // workspace layout (256B aligned slabs)
    char* p = (char*)d_ws;
    size_t off = 0;
    auto alloc = [&](size_t bytes) -> char* {
        char* r = p + off;
        off = (off + bytes + 255) & ~(size_t)255;
        return r;
    };
    int*   flag = (int*)  alloc(4);
    int*   cnt  = (int*)  alloc((size_t)NN * 4);
    int*   offs = (int*)  alloc(((size_t)NN + 1) * 4);
    int*   cur  = (int*)  alloc((size_t)NN * 4);
    float* dinv = (float*)alloc((size_t)NN * 4);
    int*   cs   = (int*)  alloc((size_t)(EE + NN) * 4);
    float* cw   = (float*)alloc((size_t)(EE + NN) * 4);
    const size_t NB = (size_t)NN * DD * 4;       // 102.4 MB
    float* bufB = (float*)alloc(NB);
    bool pathA = (ws_size >= off + NB);          // room for a 2nd big buffer?
    float* bufA = pathA ? (float*)alloc(NB) : (float*)d_out;

    // graph norm + CSR (rebuilt every call; all outputs fully overwritten)
    probe_mask_k <<<1, 64, 0, stream>>>((const unsigned int*)mask1, flag);
    init_deg_k   <<<391, 256, 0, stream>>>(cnt);
    count_deg_k  <<<6250, 256, 0, stream>>>(e_dst, cnt);
    dinv_k       <<<391, 256, 0, stream>>>(cnt, dinv);
    scan_k       <<<1, 1024, 0, stream>>>(cnt, offs);
    copy_cursor_k<<<391, 256, 0, stream>>>(offs, cur);
    fill_csr_k   <<<6250, 256, 0, stream>>>(e_src, e_dst, dinv, cur, cs, cw);
    fill_self_k  <<<391, 256, 0, stream>>>(dinv, cur, cs, cw);

    const int GB = (NN + 63) / 64;   // 1563 gemm blocks
    // layer 0: h0 = dropout(relu(omega @ W_lin + b_lin))            -> bufB
    gemm64_k<1><<<GB, 256, 0, stream>>>(omega, W_lin, b_lin, mask1, flag, bufB);
    // layer 1: t1 = h0 @ W_g1                                       -> bufA
    gemm64_k<0><<<GB, 256, 0, stream>>>(bufB, W_g1, nullptr, nullptr, flag, bufA);
    //          h1 = dropout(relu(agg(t1) + b_g1))                   -> bufB
    agg_k<1><<<NN / 4, 256, 0, stream>>>(bufA, offs, cs, cw, b_g1, mask2, flag, nullptr, bufB);
    // layer 2: t2 = h1 @ W_g2                                       -> bufA
    gemm64_k<0><<<GB, 256, 0, stream>>>(bufB, W_g2, nullptr, nullptr, flag, bufA);
    if (pathA) {
        //      out = z * (agg(t2) + b_g2)                           -> d_out
        agg_k<2><<<NN / 4, 256, 0, stream>>>(bufA, offs, cs, cw, b_g2, nullptr, flag, z, (float*)d_out);
    } else {
        // bufA aliases d_out: agg into bufB, then elementwise z-mult
        agg_k<3><<<NN / 4, 256, 0, stream>>>(bufA, offs, cs, cw, b_g2, nullptr, flag, nullptr, bufB);
        mulz_k<<<NN * DD / 4 / 256, 256, 0, stream>>>(z, bufB, (float*)d_out);
    }
}

// Round 2
// 715.710 us; speedup vs baseline: 1.9603x; 1.9603x over previous
//
#include <hip/hip_runtime.h>
#include <stdint.h>

#define NN 100000
#define EE 1600000
#define DD 256

typedef __bf16 bf16;
typedef __attribute__((ext_vector_type(8))) __bf16 bf16x8;
typedef __attribute__((ext_vector_type(4))) float f32x4;

typedef __attribute__((address_space(1))) const unsigned int g_u32c;
typedef __attribute__((address_space(3))) unsigned int lds_u32;

__device__ __forceinline__ float bflo(unsigned int u) {
    union { unsigned int u; float f; } x; x.u = u << 16; return x.f;
}
__device__ __forceinline__ float bfhi(unsigned int u) {
    union { unsigned int u; float f; } x; x.u = u & 0xFFFF0000u; return x.f;
}
__device__ __forceinline__ unsigned short f2bf(float f) {
    return __builtin_bit_cast(unsigned short, (__bf16)f);
}

// ---------------------------------------------------------------------------
// Mask dtype probe (bool may arrive byte-packed / int32 / f32)
// ---------------------------------------------------------------------------
__global__ void probe_mask_k(const unsigned int* __restrict__ m, int* __restrict__ flag) {
    unsigned int v = m[threadIdx.x];
    int bad = (v > 1u && v != 0x3F800000u) ? 1 : 0;
    unsigned long long b = __ballot(bad);
    if (threadIdx.x == 0) *flag = (b != 0ull) ? 1 : 0;
}

__device__ __forceinline__ float mask_fac(const void* mask, size_t idx, int byteMode) {
    if (byteMode) return ((const unsigned char*)mask)[idx] ? 2.0f : 0.0f;
    return ((const unsigned int*)mask)[idx] ? 2.0f : 0.0f;
}

// ---------------------------------------------------------------------------
// GCN norm + CSR build
// ---------------------------------------------------------------------------
__global__ void init_deg_k(int* __restrict__ cnt) {
    int i = blockIdx.x * 256 + threadIdx.x;
    if (i < NN) cnt[i] = 1;
}
__global__ void count_deg_k(const int* __restrict__ dst, int* __restrict__ cnt) {
    int e = blockIdx.x * 256 + threadIdx.x;
    if (e < EE) atomicAdd(&cnt[dst[e]], 1);
}
__global__ void dinv_k(const int* __restrict__ cnt, float* __restrict__ dinv) {
    int i = blockIdx.x * 256 + threadIdx.x;
    if (i < NN) dinv[i] = rsqrtf((float)cnt[i]);
}
// hierarchical scan: block-inclusive -> top exclusive -> add
__global__ __launch_bounds__(256) void scan_blk_k(const int* __restrict__ cnt,
                                                  int* __restrict__ part, int* __restrict__ bsum) {
    __shared__ int buf[256];
    int i = blockIdx.x * 256 + threadIdx.x;
    int v = (i < NN) ? cnt[i] : 0;
    buf[threadIdx.x] = v;
    __syncthreads();
    for (int off = 1; off < 256; off <<= 1) {
        int t = (threadIdx.x >= off) ? buf[threadIdx.x - off] : 0;
        __syncthreads();
        buf[threadIdx.x] += t;
        __syncthreads();
    }
    if (i < NN) part[i] = buf[threadIdx.x];
    if (threadIdx.x == 255) bsum[blockIdx.x] = buf[255];
}
__global__ __launch_bounds__(512) void scan_top_k(const int* __restrict__ bsum,
                                                  int* __restrict__ bpre, int nb) {
    __shared__ int buf[512];
    int v = (threadIdx.x < (unsigned)nb) ? bsum[threadIdx.x] : 0;
    buf[threadIdx.x] = v;
    __syncthreads();
    for (int off = 1; off < 512; off <<= 1) {
        int t = (threadIdx.x >= off) ? buf[threadIdx.x - off] : 0;
        __syncthreads();
        buf[threadIdx.x] += t;
        __syncthreads();
    }
    if (threadIdx.x < (unsigned)nb) bpre[threadIdx.x] = buf[threadIdx.x] - v;
}
__global__ void scan_add_k(const int* __restrict__ part, const int* __restrict__ bpre,
                           int* __restrict__ offs) {
    int i = blockIdx.x * 256 + threadIdx.x;
    if (i < NN) offs[i + 1] = part[i] + bpre[blockIdx.x];
    if (i == 0) offs[0] = 0;
}
__global__ void copy_cursor_k(const int* __restrict__ offs, int* __restrict__ cur) {
    int i = blockIdx.x * 256 + threadIdx.x;
    if (i < NN) cur[i] = offs[i];
}
__global__ void fill_csr_k(const int* __restrict__ src, const int* __restrict__ dst,
                           const float* __restrict__ dinv, int* __restrict__ cur,
                           int* __restrict__ cs, float* __restrict__ cw) {
    int e = blockIdx.x * 256 + threadIdx.x;
    if (e >= EE) return;
    int s = src[e], d = dst[e];
    int pos = atomicAdd(&cur[d], 1);
    cs[pos] = s;
    cw[pos] = dinv[s] * dinv[d];
}
__global__ void fill_self_k(const float* __restrict__ dinv, int* __restrict__ cur,
                            int* __restrict__ cs, float* __restrict__ cw) {
    int i = blockIdx.x * 256 + threadIdx.x;
    if (i >= NN) return;
    int pos = atomicAdd(&cur[i], 1);
    cs[pos] = i;
    float di = dinv[i];
    cw[pos] = di * di;
}

// ---------------------------------------------------------------------------
// conversions
// ---------------------------------------------------------------------------
__global__ void cvt_rows_k(const float* __restrict__ in, unsigned short* __restrict__ out, int n4) {
    int i = blockIdx.x * 256 + threadIdx.x;
    if (i < n4) {
        float4 v = ((const float4*)in)[i];
        ushort4 o = { f2bf(v.x), f2bf(v.y), f2bf(v.z), f2bf(v.w) };
        ((ushort4*)out)[i] = o;
    }
}
// Wt[n][k] = (bf16)W[k][n], 256x256, grid 64 blocks of 256 (32x8)
__global__ void cvt_wT_k(const float* __restrict__ W, bf16* __restrict__ Wt) {
    __shared__ float tile[32][33];
    int bx = blockIdx.x & 7, by = blockIdx.x >> 3;
    int tx = threadIdx.x & 31, ty = threadIdx.x >> 5;
    #pragma unroll
    for (int r = 0; r < 32; r += 8)
        tile[ty + r][tx] = W[(size_t)(by * 32 + ty + r) * DD + bx * 32 + tx];
    __syncthreads();
    #pragma unroll
    for (int r = 0; r < 32; r += 8)
        Wt[(size_t)(bx * 32 + ty + r) * DD + by * 32 + tx] = (bf16)tile[tx][ty + r];
}

// ---------------------------------------------------------------------------
// bf16 MFMA GEMM: out[M,256] = A[M,256] @ W, W given as Wt[n][k].
// 128x128 tile, BK=64, 256 thr = 4 waves (2x2), 4x4 16x16x32 frags/wave.
// EPI 0: store bf16 raw.  EPI 1: bias+relu+dropout -> bf16.
// ---------------------------------------------------------------------------
template <int EPI>
__global__ __launch_bounds__(256) void gemm_bf16_k(
    const bf16* __restrict__ A, const bf16* __restrict__ Wt,
    const float* __restrict__ bias, const void* __restrict__ mask,
    const int* __restrict__ flagp, bf16* __restrict__ outb) {
    __shared__ __align__(16) bf16 As[128 * 64];
    __shared__ __align__(16) bf16 Bs[128 * 64];
    int tid = threadIdx.x;
    int m0 = blockIdx.x * 128;
    int n0 = blockIdx.y * 128;
    int wid = tid >> 6, lane = tid & 63;
    int wm = wid >> 1, wn = wid & 1;
    int lr = lane & 15, lk = lane >> 4;

    f32x4 acc[4][4] = {};

    for (int k0 = 0; k0 < 256; k0 += 64) {
        #pragma unroll
        for (int i = 0; i < 4; i++) {
            int f = i * 256 + tid;            // 16B chunk id, 1024 chunks per tile
            int row = f >> 3;                 // 8 chunks per 64-elem row
            int col = (f & 7) * 8;
            int gr = m0 + row; if (gr > NN - 1) gr = NN - 1;
            __builtin_amdgcn_global_load_lds(
                (g_u32c*)(A + (size_t)gr * DD + k0 + col),
                (lds_u32*)(As + (size_t)f * 8), 16, 0, 0);
            __builtin_amdgcn_global_load_lds(
                (g_u32c*)(Wt + (size_t)(n0 + row) * DD + k0 + col),
                (lds_u32*)(Bs + (size_t)f * 8), 16, 0, 0);
        }
        __syncthreads();
        #pragma unroll
        for (int kk = 0; kk < 2; kk++) {
            bf16x8 af[4], bfr[4];
            #pragma unroll
            for (int mi = 0; mi < 4; mi++)
                af[mi] = *(const bf16x8*)(As + (wm * 64 + mi * 16 + lr) * 64 + kk * 32 + lk * 8);
            #pragma unroll
            for (int ni = 0; ni < 4; ni++)
                bfr[ni] = *(const bf16x8*)(Bs + (wn * 64 + ni * 16 + lr) * 64 + kk * 32 + lk * 8);
            #pragma unroll
            for (int mi = 0; mi < 4; mi++)
                #pragma unroll
                for (int ni = 0; ni < 4; ni++)
                    acc[mi][ni] = __builtin_amdgcn_mfma_f32_16x16x32_bf16(
                        af[mi], bfr[ni], acc[mi][ni], 0, 0, 0);
        }
        __syncthreads();
    }

    int bm = (EPI == 1) ? *flagp : 0;
    #pragma unroll
    for (int mi = 0; mi < 4; mi++) {
        #pragma unroll
        for (int r = 0; r < 4; r++) {
            int gr = m0 + wm * 64 + mi * 16 + lk * 4 + r;   // C/D: row=(lane>>4)*4+r
            if (gr >= NN) continue;
            #pragma unroll
            for (int ni = 0; ni < 4; ni++) {
                int gc = n0 + wn * 64 + ni * 16 + lr;       // col = lane&15
                float v = acc[mi][ni][r];
                if (EPI == 1) {
                    v = fmaxf(v + bias[gc], 0.0f);
                    v *= mask_fac(mask, (size_t)gr * DD + gc, bm);
                }
                outb[(size_t)gr * DD + gc] = (bf16)v;
            }
        }
    }
}

// ---------------------------------------------------------------------------
// CSR pull aggregation over bf16 rows (512B each), fp32 accumulate.
// One wave per node, lane owns 4 cols (8B gather).
// EPI 1: +bias, relu, dropout -> bf16.  EPI 2: (+bias)*z -> fp32 d_out.
// ---------------------------------------------------------------------------
template <int EPI>
__global__ __launch_bounds__(256) void agg_bf16_k(
    const bf16* __restrict__ t, const int* __restrict__ offs,
    const int* __restrict__ cs, const float* __restrict__ cw,
    const float* __restrict__ bias, const void* __restrict__ mask,
    const int* __restrict__ flagp, const float* __restrict__ z,
    bf16* __restrict__ outb, float* __restrict__ outf) {
    int node = blockIdx.x * 4 + (threadIdx.x >> 6);
    if (node >= NN) return;
    int lane = threadIdx.x & 63;
    int beg = offs[node], end = offs[node + 1];

    float4 acc = {0.f, 0.f, 0.f, 0.f};
    const unsigned short* tb = (const unsigned short*)t;
    for (int base = beg; base < end; base += 64) {
        int nume = min(64, end - base);
        int sl = 0; float wl = 0.f;
        if (lane < nume) { sl = cs[base + lane]; wl = cw[base + lane]; }
        for (int j = 0; j < nume; j++) {
            int s   = __shfl(sl, j);
            float w = __shfl(wl, j);
            uint2 u = *(const uint2*)(tb + (size_t)s * DD + lane * 4);
            acc.x = fmaf(w, bflo(u.x), acc.x);
            acc.y = fmaf(w, bfhi(u.x), acc.y);
            acc.z = fmaf(w, bflo(u.y), acc.z);
            acc.w = fmaf(w, bfhi(u.y), acc.w);
        }
    }

    int col = lane * 4;
    float4 b = *(const float4*)(bias + col);
    acc.x += b.x; acc.y += b.y; acc.z += b.z; acc.w += b.w;
    size_t idx = (size_t)node * DD + col;

    if (EPI == 1) {
        int bm = *flagp;
        acc.x = fmaxf(acc.x, 0.f) * mask_fac(mask, idx + 0, bm);
        acc.y = fmaxf(acc.y, 0.f) * mask_fac(mask, idx + 1, bm);
        acc.z = fmaxf(acc.z, 0.f) * mask_fac(mask, idx + 2, bm);
        acc.w = fmaxf(acc.w, 0.f) * mask_fac(mask, idx + 3, bm);
        ushort4 o = { f2bf(acc.x), f2bf(acc.y), f2bf(acc.z), f2bf(acc.w) };
        *(ushort4*)((unsigned short*)outb + idx) = o;
    } else {
        float4 zz = *(const float4*)(z + idx);
        acc.x *= zz.x; acc.y *= zz.y; acc.z *= zz.z; acc.w *= zz.w;
        *(float4*)(outf + idx) = acc;
    }
}

// ---------------------------------------------------------------------------
extern "C" void kernel_launch(void* const* d_in, const int* in_sizes, int n_in,
                              void* d_out, int out_size, void* d_ws, size_t ws_size,
                              hipStream_t stream) {
    const float* z     = (const float*)d_in[0];
    const float* omega = (const float*)d_in[1];
    const int*   eidx  = (const int*)d_in[2];
    const float* W_lin = (const float*)d_in[3];
    const float* b_lin = (const float*)d_in[4];
    const float* W_g1  = (const float*)d_in[5];
    const float* b_g1  = (const float*)d_in[6];
    const float* W_g2  = (const float*)d_in[7];
    const float* b_g2  = (const float*)d_in[8];
    const void*  mask1 = d_in[9];
    const void*  mask2 = d_in[10];

    const int* e_src = eidx;
    const int* e_dst = eidx + EE;

    char* p = (char*)d_ws;
    size_t off = 0;
    auto alloc = [&](size_t bytes) -> char* {
        char* r = p + off;
        off = (off + bytes + 255) & ~(size_t)255;
        return r;
    };
    const int NB256 = (NN + 255) / 256;          // 391
    int*   flag = (int*)  alloc(4);
    int*   cnt  = (int*)  alloc((size_t)NN * 4);
    int*   offs = (int*)  alloc(((size_t)NN + 1) * 4);
    int*   cur  = (int*)  alloc((size_t)NN * 4);
    int*   part = (int*)  alloc((size_t)NN * 4);
    int*   bsum = (int*)  alloc(512 * 4);
    int*   bpre = (int*)  alloc(512 * 4);
    float* dinv = (float*)alloc((size_t)NN * 4);
    int*   cs   = (int*)  alloc((size_t)(EE + NN) * 4);
    float* cw   = (float*)alloc((size_t)(EE + NN) * 4);
    bf16*  WtL  = (bf16*) alloc((size_t)DD * DD * 2);
    bf16*  Wt1  = (bf16*) alloc((size_t)DD * DD * 2);
    bf16*  Wt2  = (bf16*) alloc((size_t)DD * DD * 2);
    const size_t NBH = (size_t)NN * DD * 2;      // 51.2 MB bf16 slab
    bf16*  S1   = (bf16*) alloc(NBH);
    bf16*  S2   = (bf16*) alloc(NBH);

    // --- graph norm + CSR ---
    probe_mask_k <<<1, 64, 0, stream>>>((const unsigned int*)mask1, flag);
    init_deg_k   <<<NB256, 256, 0, stream>>>(cnt);
    count_deg_k  <<<EE / 256, 256, 0, stream>>>(e_dst, cnt);
    dinv_k       <<<NB256, 256, 0, stream>>>(cnt, dinv);
    scan_blk_k   <<<NB256, 256, 0, stream>>>(cnt, part, bsum);
    scan_top_k   <<<1, 512, 0, stream>>>(bsum, bpre, NB256);
    scan_add_k   <<<NB256, 256, 0, stream>>>(part, bpre, offs);
    copy_cursor_k<<<NB256, 256, 0, stream>>>(offs, cur);
    fill_csr_k   <<<EE / 256, 256, 0, stream>>>(e_src, e_dst, dinv, cur, cs, cw);
    fill_self_k  <<<NB256, 256, 0, stream>>>(dinv, cur, cs, cw);

    // --- conversions ---
    cvt_rows_k<<<NN * DD / 4 / 256, 256, 0, stream>>>(omega, (unsigned short*)S1, NN * DD / 4);
    cvt_wT_k  <<<64, 256, 0, stream>>>(W_lin, WtL);
    cvt_wT_k  <<<64, 256, 0, stream>>>(W_g1, Wt1);
    cvt_wT_k  <<<64, 256, 0, stream>>>(W_g2, Wt2);

    // --- pipeline ---
    dim3 ggrid((NN + 127) / 128, 2);
    // h0 = dropout(relu(omega @ W_lin + b_lin))            S1 -> S2
    gemm_bf16_k<1><<<ggrid, 256, 0, stream>>>(S1, WtL, b_lin, mask1, flag, S2);
    // t1 = h0 @ W_g1                                       S2 -> S1
    gemm_bf16_k<0><<<ggrid, 256, 0, stream>>>(S2, Wt1, nullptr, nullptr, flag, S1);
    // h1 = dropout(relu(agg(t1) + b_g1))                   S1 -> S2
    agg_bf16_k<1><<<NN / 4, 256, 0, stream>>>(S1, offs, cs, cw, b_g1, mask2, flag,
                                              nullptr, S2, nullptr);
    // t2 = h1 @ W_g2                                       S2 -> S1
    gemm_bf16_k<0><<<ggrid, 256, 0, stream>>>(S2, Wt2, nullptr, nullptr, flag, S1);
    // out = z * (agg(t2) + b_g2)                           S1 -> d_out (fp32)
    agg_bf16_k<2><<<NN / 4, 256, 0, stream>>>(S1, offs, cs, cw, b_g2, nullptr, flag,
                                              z, nullptr, (float*)d_out);
}